// Round 2
// baseline (670.193 us; speedup 1.0000x reference)
//
#include <hip/hip_runtime.h>
#include <math.h>

#define EMB_DIM 128
#define DISC_HIDDEN 512
#define MARGIN 24.0f
#define BATCH 4096
#define NEG 64

__device__ __forceinline__ float logsig(float x) {
    // stable log(sigmoid(x)) = min(x,0) - log1p(exp(-|x|))
    return fminf(x, 0.0f) - log1pf(expf(-fabsf(x)));
}

// ---------------------------------------------------------------------------
// One block (256 thr = 4 waves) per batch element b.
//  phase 0 : stage 192 neg indices -> LDS; pos diff -> LDS (threads 0..127)
//  phase A : 16 negs per wave, one neg per full wave (float2 lanes),
//            indices from LDS (no HBM dependency in the loop)
//  phase B : MLP, thread t owns hidden units 2t,2t+1 (coalesced float2 W1)
//  final   : thread 0 combines -> partial[b]  (no atomics)
// ---------------------------------------------------------------------------
__global__ __launch_bounds__(256, 4) void fused_kernel(
    const int*   __restrict__ pos_triples,   // (B, 3)
    const int*   __restrict__ neg_triples,   // (B, NEG, 3)
    const float* __restrict__ ent,           // (1e6, 128)
    const float* __restrict__ rel,           // (1000, 128)
    const float* __restrict__ W1,            // (128, 512) row-major
    const float* __restrict__ b1,            // (512)
    const float* __restrict__ W2,            // (512)
    const float* __restrict__ b2,            // (1)
    float*       __restrict__ partial)       // (B) workspace
{
    const int b    = blockIdx.x;
    const int tid  = threadIdx.x;
    const int wave = tid >> 6;
    const int lane = tid & 63;

    __shared__ int   s_idx[NEG * 3];                  // 768 B
    __shared__ __align__(16) float s_diff[EMB_DIM];   // 512 B
    __shared__ float s_dpos[2];
    __shared__ float s_wacc[4];
    __shared__ float s_z[4];

    // ---- phase 0: stage neg indices ----
    if (tid < NEG * 3) s_idx[tid] = neg_triples[(size_t)b * (NEG * 3) + tid];

    // ---- phase 0b: positive diff (threads 0..127, one dim each) ----
    if (tid < EMB_DIM) {
        const int ph = pos_triples[b * 3 + 0];
        const int pr = pos_triples[b * 3 + 1];
        const int pt = pos_triples[b * 3 + 2];
        const float d = ent[(size_t)ph * EMB_DIM + tid]
                      + rel[(size_t)pr * EMB_DIM + tid]
                      - ent[(size_t)pt * EMB_DIM + tid];
        s_diff[tid] = d;
        float s = fabsf(d);
        s += __shfl_xor(s, 32);
        s += __shfl_xor(s, 16);
        s += __shfl_xor(s, 8);
        s += __shfl_xor(s, 4);
        s += __shfl_xor(s, 2);
        s += __shfl_xor(s, 1);
        if (lane == 0) s_dpos[wave] = s;
    }
    __syncthreads();

    // ---- phase A: negatives. one neg per wave-iteration, float2 per lane ----
    float acc = 0.0f;
    #pragma unroll 4
    for (int i = 0; i < 16; ++i) {
        const int n  = wave * 16 + i;
        const int ih = s_idx[n * 3 + 0];
        const int ir = s_idx[n * 3 + 1];
        const int it = s_idx[n * 3 + 2];
        const float2 h2 = *(const float2*)(ent + (size_t)ih * EMB_DIM + lane * 2);
        const float2 r2 = *(const float2*)(rel + (size_t)ir * EMB_DIM + lane * 2);
        const float2 t2 = *(const float2*)(ent + (size_t)it * EMB_DIM + lane * 2);
        float s = fabsf(h2.x + r2.x - t2.x) + fabsf(h2.y + r2.y - t2.y);
        s += __shfl_xor(s, 32);
        s += __shfl_xor(s, 16);
        s += __shfl_xor(s, 8);
        s += __shfl_xor(s, 4);
        s += __shfl_xor(s, 2);
        s += __shfl_xor(s, 1);
        acc += logsig(MARGIN - s);
    }
    if (lane == 0) s_wacc[wave] = acc;
    // no barrier needed before phase B: s_diff was written before the first
    // __syncthreads and is read-only from here on.

    // ---- phase B: MLP. thread t -> hidden units j=2t, 2t+1 ----
    {
        const float2 bb = *(const float2*)(b1 + 2 * tid);
        float a0 = bb.x, a1 = bb.y;
        #pragma unroll 4
        for (int k = 0; k < EMB_DIM; k += 4) {
            const float4 d4 = *(const float4*)(s_diff + k);
            const float2 w0 = *(const float2*)(W1 + (k + 0) * DISC_HIDDEN + 2 * tid);
            const float2 w1 = *(const float2*)(W1 + (k + 1) * DISC_HIDDEN + 2 * tid);
            const float2 w2 = *(const float2*)(W1 + (k + 2) * DISC_HIDDEN + 2 * tid);
            const float2 w3 = *(const float2*)(W1 + (k + 3) * DISC_HIDDEN + 2 * tid);
            a0 = fmaf(d4.x, w0.x, a0);  a1 = fmaf(d4.x, w0.y, a1);
            a0 = fmaf(d4.y, w1.x, a0);  a1 = fmaf(d4.y, w1.y, a1);
            a0 = fmaf(d4.z, w2.x, a0);  a1 = fmaf(d4.z, w2.y, a1);
            a0 = fmaf(d4.w, w3.x, a0);  a1 = fmaf(d4.w, w3.y, a1);
        }
        const float2 v2 = *(const float2*)(W2 + 2 * tid);
        float zp = fmaxf(a0, 0.0f) * v2.x + fmaxf(a1, 0.0f) * v2.y;
        zp += __shfl_xor(zp, 32);
        zp += __shfl_xor(zp, 16);
        zp += __shfl_xor(zp, 8);
        zp += __shfl_xor(zp, 4);
        zp += __shfl_xor(zp, 2);
        zp += __shfl_xor(zp, 1);
        if (lane == 0) s_z[wave] = zp;
    }
    __syncthreads();

    // ---- final: combine ----
    if (tid == 0) {
        const float z    = s_z[0] + s_z[1] + s_z[2] + s_z[3] + b2[0];
        const float conf = 1.0f / (1.0f + expf(-z));
        const float dpos = s_dpos[0] + s_dpos[1];
        const float pt   = -logsig(MARGIN - dpos);
        const float nt   = (s_wacc[0] + s_wacc[1] + s_wacc[2] + s_wacc[3]) * (1.0f / NEG);
        partial[b] = conf * (pt + nt);
    }
}

// ---------------------------------------------------------------------------
// Final reduction of 4096 per-b partials -> d_out[0]
// ---------------------------------------------------------------------------
__global__ __launch_bounds__(256) void finalize_kernel(
    const float* __restrict__ partial, float* __restrict__ out)
{
    float s = 0.0f;
    #pragma unroll
    for (int i = 0; i < BATCH / 256; ++i) s += partial[i * 256 + threadIdx.x];
    s += __shfl_xor(s, 32);
    s += __shfl_xor(s, 16);
    s += __shfl_xor(s, 8);
    s += __shfl_xor(s, 4);
    s += __shfl_xor(s, 2);
    s += __shfl_xor(s, 1);
    __shared__ float ws[4];
    if ((threadIdx.x & 63) == 0) ws[threadIdx.x >> 6] = s;
    __syncthreads();
    if (threadIdx.x == 0) out[0] = ws[0] + ws[1] + ws[2] + ws[3];
}

extern "C" void kernel_launch(void* const* d_in, const int* in_sizes, int n_in,
                              void* d_out, int out_size, void* d_ws, size_t ws_size,
                              hipStream_t stream) {
    const int*   pos_triples = (const int*)  d_in[0];
    const int*   neg_triples = (const int*)  d_in[1];
    // d_in[2] = negative_sample_size (compile-time NEG)
    const float* ent         = (const float*)d_in[3];
    const float* rel         = (const float*)d_in[4];
    const float* W1          = (const float*)d_in[5];
    const float* b1          = (const float*)d_in[6];
    const float* W2          = (const float*)d_in[7];
    const float* b2          = (const float*)d_in[8];
    float* out     = (float*)d_out;
    float* partial = (float*)d_ws;   // BATCH floats

    fused_kernel<<<BATCH, 256, 0, stream>>>(pos_triples, neg_triples, ent, rel,
                                            W1, b1, W2, b2, partial);
    finalize_kernel<<<1, 256, 0, stream>>>(partial, out);
}